// Round 1
// baseline (2728.720 us; speedup 1.0000x reference)
//
#include <hip/hip_runtime.h>
#include <hip/hip_bf16.h>

#define HF 64   // hidden features

// ---- degree init: deg[n] = 1.0 (self loop) ----
__global__ void k_init_deg(float* __restrict__ deg, int N) {
    int i = blockIdx.x * blockDim.x + threadIdx.x;
    if (i < N) deg[i] = 1.0f;
}

// ---- degree count: deg[dst[e]] += 1 ----
__global__ void k_count_deg(float* __restrict__ deg, const int* __restrict__ dst, int E) {
    int e = blockIdx.x * blockDim.x + threadIdx.x;
    if (e < E) atomicAdd(&deg[dst[e]], 1.0f);
}

// ---- dinv[n] = rsqrt(deg[n]) in place ----
__global__ void k_rsqrt(float* __restrict__ deg, int N) {
    int i = blockIdx.x * blockDim.x + threadIdx.x;
    if (i < N) deg[i] = rsqrtf(deg[i]);
}

// ---- enorm[e] = dinv[src]*dinv[dst] ----
__global__ void k_enorm(float* __restrict__ enorm, const float* __restrict__ dinv,
                        const int* __restrict__ src, const int* __restrict__ dst, int E) {
    int e = blockIdx.x * blockDim.x + threadIdx.x;
    if (e < E) enorm[e] = dinv[src[e]] * dinv[dst[e]];
}

// ---- Y[N,64] = X[N,K] @ W[K,64] ----
template <int K>
__global__ void k_matmul(const float* __restrict__ X, const float* __restrict__ W,
                         float* __restrict__ Y, int N) {
    __shared__ float sW[K * HF];
    for (int i = threadIdx.x; i < K * HF; i += blockDim.x) sW[i] = W[i];
    __syncthreads();
    int i = blockIdx.x * blockDim.x + threadIdx.x;
    if (i >= N * HF) return;
    int n = i >> 6, f = i & 63;
    const float* xr = X + n * K;
    float acc = 0.f;
#pragma unroll
    for (int k = 0; k < K; ++k) acc += xr[k] * sW[k * HF + f];
    Y[i] = acc;
}

// ---- agg[dst] += hw[src] * enorm : one lane per (edge, feature) ----
__global__ void k_aggregate(const float* __restrict__ hw, float* __restrict__ agg,
                            const int* __restrict__ src, const int* __restrict__ dst,
                            const float* __restrict__ enorm, int E) {
    long long tid = (long long)blockIdx.x * blockDim.x + threadIdx.x;
    int e = (int)(tid >> 6);
    if (e >= E) return;
    int f = (int)(tid & 63);
    int s = src[e], d = dst[e];
    float v = hw[s * HF + f] * enorm[e];
    atomicAdd(&agg[d * HF + f], v);
}

// ---- epilogue: h = relu(bn(agg + hw*dinv^2 + b)) in place on agg ----
__global__ void k_finish(const float* __restrict__ hw, float* __restrict__ agg,
                         const float* __restrict__ dinv,
                         const float* __restrict__ b, const float* __restrict__ g,
                         const float* __restrict__ be, const float* __restrict__ rm,
                         const float* __restrict__ rv, int NF) {
    int i = blockIdx.x * blockDim.x + threadIdx.x;
    if (i >= NF) return;
    int n = i >> 6, f = i & 63;
    float di = dinv[n];
    float v = agg[i] + hw[i] * di * di + b[f];
    float scale = g[f] * rsqrtf(rv[f] + 1e-5f);
    v = (v - rm[f]) * scale + be[f];
    agg[i] = fmaxf(v, 0.f);
}

// ---- per-graph mean-pool + FC(64->32) relu + FC(32->2) sigmoid ----
// one block of 64 threads per graph; batch is sorted.
__global__ void k_pool_fc(const float* __restrict__ h, const int* __restrict__ batch,
                          const float* __restrict__ Wf1, const float* __restrict__ bf1,
                          const float* __restrict__ Wf2, const float* __restrict__ bf2,
                          float* __restrict__ out, int N) {
    int g = blockIdx.x;
    int f = threadIdx.x;  // 0..63
    // lower_bound(g) and lower_bound(g+1) over sorted batch
    int lo = 0, hi = N;
    while (lo < hi) { int mid = (lo + hi) >> 1; if (batch[mid] < g) lo = mid + 1; else hi = mid; }
    int start = lo;
    hi = N;
    while (lo < hi) { int mid = (lo + hi) >> 1; if (batch[mid] < g + 1) lo = mid + 1; else hi = mid; }
    int end = lo;

    float sum = 0.f;
    for (int n = start; n < end; ++n) sum += h[n * HF + f];
    float cnt = (float)(end - start);
    float pooled = sum / fmaxf(cnt, 1.0f);

    __shared__ float sp[HF];
    __shared__ float sh[32];
    sp[f] = pooled;
    __syncthreads();
    if (f < 32) {
        float a = bf1[f];
#pragma unroll
        for (int k = 0; k < HF; ++k) a += sp[k] * Wf1[k * 32 + f];
        sh[f] = fmaxf(a, 0.f);
    }
    __syncthreads();
    if (f < 2) {
        float a = bf2[f];
#pragma unroll
        for (int k = 0; k < 32; ++k) a += sh[k] * Wf2[k * 2 + f];
        out[g * 2 + f] = 1.f / (1.f + expf(-a));
    }
}

extern "C" void kernel_launch(void* const* d_in, const int* in_sizes, int n_in,
                              void* d_out, int out_size, void* d_ws, size_t ws_size,
                              hipStream_t stream) {
    const float* x     = (const float*)d_in[0];
    const int*   ei    = (const int*)d_in[1];
    const int*   batch = (const int*)d_in[2];
    const float* W1 = (const float*)d_in[3];
    const float* b1 = (const float*)d_in[4];
    const float* g1 = (const float*)d_in[5];
    const float* be1 = (const float*)d_in[6];
    const float* rm1 = (const float*)d_in[7];
    const float* rv1 = (const float*)d_in[8];
    const float* W2 = (const float*)d_in[9];
    const float* b2 = (const float*)d_in[10];
    const float* g2 = (const float*)d_in[11];
    const float* be2 = (const float*)d_in[12];
    const float* rm2 = (const float*)d_in[13];
    const float* rv2 = (const float*)d_in[14];
    const float* W3 = (const float*)d_in[15];
    const float* b3 = (const float*)d_in[16];
    const float* g3 = (const float*)d_in[17];
    const float* be3 = (const float*)d_in[18];
    const float* rm3 = (const float*)d_in[19];
    const float* rv3 = (const float*)d_in[20];
    const float* Wf1 = (const float*)d_in[21];
    const float* bf1 = (const float*)d_in[22];
    const float* Wf2 = (const float*)d_in[23];
    const float* bf2 = (const float*)d_in[24];
    float* out = (float*)d_out;

    const int N = in_sizes[2];          // 100000
    const int E = in_sizes[1] / 2;      // 3200000
    const int G = out_size / 2;         // 256

    // workspace layout (256B aligned)
    char* ws = (char*)d_ws;
    size_t off = 0;
    auto alloc = [&](size_t bytes) {
        char* p = ws + off;
        off += (bytes + 255) & ~(size_t)255;
        return p;
    };
    float* A     = (float*)alloc((size_t)N * HF * sizeof(float));  // hw
    float* B     = (float*)alloc((size_t)N * HF * sizeof(float));  // agg / h
    float* deg   = (float*)alloc((size_t)N * sizeof(float));       // deg -> dinv
    float* enorm = (float*)alloc((size_t)E * sizeof(float));

    const int* src = ei;
    const int* dst = ei + E;

    const int BT = 256;
    int gN   = (N + BT - 1) / BT;
    int gE   = (E + BT - 1) / BT;
    int gNF  = (N * HF + BT - 1) / BT;
    long long eft = (long long)E * HF;
    int gEF  = (int)((eft + BT - 1) / BT);

    // normalization precompute
    k_init_deg<<<gN, BT, 0, stream>>>(deg, N);
    k_count_deg<<<gE, BT, 0, stream>>>(deg, dst, E);
    k_rsqrt<<<gN, BT, 0, stream>>>(deg, N);
    k_enorm<<<gE, BT, 0, stream>>>(enorm, deg, src, dst, E);

    // ---- layer 1 ----
    k_matmul<5><<<gNF, BT, 0, stream>>>(x, W1, A, N);
    hipMemsetAsync(B, 0, (size_t)N * HF * sizeof(float), stream);
    k_aggregate<<<gEF, BT, 0, stream>>>(A, B, src, dst, enorm, E);
    k_finish<<<gNF, BT, 0, stream>>>(A, B, deg, b1, g1, be1, rm1, rv1, N * HF);

    // ---- layer 2 ----
    k_matmul<64><<<gNF, BT, 0, stream>>>(B, W2, A, N);
    hipMemsetAsync(B, 0, (size_t)N * HF * sizeof(float), stream);
    k_aggregate<<<gEF, BT, 0, stream>>>(A, B, src, dst, enorm, E);
    k_finish<<<gNF, BT, 0, stream>>>(A, B, deg, b2, g2, be2, rm2, rv2, N * HF);

    // ---- layer 3 ----
    k_matmul<64><<<gNF, BT, 0, stream>>>(B, W3, A, N);
    hipMemsetAsync(B, 0, (size_t)N * HF * sizeof(float), stream);
    k_aggregate<<<gEF, BT, 0, stream>>>(A, B, src, dst, enorm, E);
    k_finish<<<gNF, BT, 0, stream>>>(A, B, deg, b3, g3, be3, rm3, rv3, N * HF);

    // ---- pool + MLP head ----
    k_pool_fc<<<G, HF, 0, stream>>>(B, batch, Wf1, bf1, Wf2, bf2, out, N);
}

// Round 2
// 1223.801 us; speedup vs baseline: 2.2297x; 2.2297x over previous
//
#include <hip/hip_runtime.h>
#include <hip/hip_bf16.h>

#define HF 64
#define EPS 1e-5f
#define SCAN_B 1024

// ---- histogram of dst (in-degree, excluding self loop) ----
__global__ void k_hist(int* __restrict__ cnt, const int* __restrict__ dst, int E) {
    int e = blockIdx.x * blockDim.x + threadIdx.x;
    if (e < E) atomicAdd(&cnt[dst[e]], 1);
}

// ---- dinv[n] = rsqrt(cnt[n] + 1) ----
__global__ void k_dinv(float* __restrict__ dinv, const int* __restrict__ cnt, int N) {
    int i = blockIdx.x * blockDim.x + threadIdx.x;
    if (i < N) dinv[i] = rsqrtf((float)cnt[i] + 1.0f);
}

// ---- scan stage 1: per-1024-chunk exclusive scan + chunk totals ----
__global__ void k_scan1(const int* __restrict__ cnt, int* __restrict__ chunk_scan,
                        int* __restrict__ bsum, int N) {
    __shared__ int tmp[2][SCAN_B];
    int t = threadIdx.x;
    int gid = blockIdx.x * SCAN_B + t;
    int v = (gid < N) ? cnt[gid] : 0;
    int pi = 0;
    tmp[0][t] = v;
    __syncthreads();
    for (int off = 1; off < SCAN_B; off <<= 1) {
        int val = tmp[pi][t];
        if (t >= off) val += tmp[pi][t - off];
        tmp[pi ^ 1][t] = val;
        pi ^= 1;
        __syncthreads();
    }
    int inc = tmp[pi][t];
    if (gid < N) chunk_scan[gid] = inc - v;   // exclusive within chunk
    if (t == SCAN_B - 1) bsum[blockIdx.x] = inc;
}

// ---- scan stage 2: exclusive scan of chunk totals (single thread, NB<=128) ----
__global__ void k_scan2(const int* __restrict__ bsum, int* __restrict__ bbase, int NB) {
    if (threadIdx.x == 0 && blockIdx.x == 0) {
        int acc = 0;
        for (int i = 0; i < NB; ++i) { bbase[i] = acc; acc += bsum[i]; }
    }
}

// ---- scan stage 3: base = chunk_scan + bbase; cursor = base ----
__global__ void k_scan3(const int* __restrict__ chunk_scan, const int* __restrict__ bbase,
                        int* __restrict__ base, int* __restrict__ cursor, int N) {
    int gid = blockIdx.x * SCAN_B + threadIdx.x;
    if (gid < N) {
        int b = chunk_scan[gid] + bbase[blockIdx.x];
        base[gid] = b;
        cursor[gid] = b;
    }
}

// ---- scatter edges into CSR buckets; w = dinv[src]*dinv[dst] ----
__global__ void k_scatter(const int* __restrict__ src, const int* __restrict__ dst,
                          const float* __restrict__ dinv, int* __restrict__ cursor,
                          int* __restrict__ csr_src, float* __restrict__ csr_w, int E) {
    int e = blockIdx.x * blockDim.x + threadIdx.x;
    if (e >= E) return;
    int s = src[e], d = dst[e];
    int pos = atomicAdd(&cursor[d], 1);
    csr_src[pos] = s;
    csr_w[pos] = dinv[s] * dinv[d];
}

// ---- Y[N,64] = X[N,K] @ W[K,64] ----
template <int K>
__global__ void k_matmul(const float* __restrict__ X, const float* __restrict__ W,
                         float* __restrict__ Y, int N) {
    __shared__ float sW[K * HF];
    for (int i = threadIdx.x; i < K * HF; i += blockDim.x) sW[i] = W[i];
    __syncthreads();
    int i = blockIdx.x * blockDim.x + threadIdx.x;
    if (i >= N * HF) return;
    int n = i >> 6, f = i & 63;
    const float* xr = X + n * K;
    float acc = 0.f;
#pragma unroll
    for (int k = 0; k < K; ++k) acc += xr[k] * sW[k * HF + f];
    Y[i] = acc;
}

// ---- segment-reduced aggregation + fused epilogue ----
// one wave (64 lanes) per node; lane = feature.
// h_out[n] = relu(bn(sum_{e in CSR[n]} hw[src_e]*w_e + hw[n]*dinv[n]^2 + b))
__global__ void k_agg(const float* __restrict__ hw, float* __restrict__ hout,
                      const int* __restrict__ csr_src, const float* __restrict__ csr_w,
                      const int* __restrict__ base, const int* __restrict__ rowend,
                      const float* __restrict__ dinv,
                      const float* __restrict__ b, const float* __restrict__ g,
                      const float* __restrict__ be, const float* __restrict__ rm,
                      const float* __restrict__ rv, int N) {
    int node = blockIdx.x * (blockDim.x >> 6) + (threadIdx.x >> 6);
    int lane = threadIdx.x & 63;
    if (node >= N) return;

    int j = base[node];
    int end = rowend[node];   // cursor after scatter == base + cnt
    float acc = 0.f;
    while (j < end) {
        int chunk = end - j;
        if (chunk > 64) chunk = 64;
        int s = 0; float w = 0.f;
        if (lane < chunk) { s = csr_src[j + lane]; w = csr_w[j + lane]; }
        for (int k = 0; k < chunk; ++k) {
            int ss = __shfl(s, k, 64);
            float ww = __shfl(w, k, 64);
            acc += hw[ss * HF + lane] * ww;
        }
        j += chunk;
    }
    float di = dinv[node];
    float v = acc + hw[node * HF + lane] * di * di + b[lane];
    v = (v - rm[lane]) * (g[lane] * rsqrtf(rv[lane] + EPS)) + be[lane];
    hout[node * HF + lane] = fmaxf(v, 0.f);
}

// ---- per-graph mean-pool + FC(64->32) relu + FC(32->2) sigmoid ----
// one block of 256 threads per graph (4-way row split); batch sorted.
__global__ void k_pool_fc(const float* __restrict__ h, const int* __restrict__ batch,
                          const float* __restrict__ Wf1, const float* __restrict__ bf1,
                          const float* __restrict__ Wf2, const float* __restrict__ bf2,
                          float* __restrict__ out, int N) {
    int g = blockIdx.x;
    int t = threadIdx.x;
    int f = t & 63, q = t >> 6;   // q in 0..3

    int lo = 0, hi = N;
    while (lo < hi) { int mid = (lo + hi) >> 1; if (batch[mid] < g) lo = mid + 1; else hi = mid; }
    int start = lo;
    hi = N;
    while (lo < hi) { int mid = (lo + hi) >> 1; if (batch[mid] < g + 1) lo = mid + 1; else hi = mid; }
    int end = lo;

    float sum = 0.f;
    for (int n = start + q; n < end; n += 4) sum += h[n * HF + f];

    __shared__ float red[4][HF];
    __shared__ float sp[HF];
    __shared__ float sh[32];
    red[q][f] = sum;
    __syncthreads();
    if (q == 0) {
        float s = red[0][f] + red[1][f] + red[2][f] + red[3][f];
        float cntf = (float)(end - start);
        sp[f] = s / fmaxf(cntf, 1.0f);
    }
    __syncthreads();
    if (t < 32) {
        float a = bf1[t];
#pragma unroll
        for (int k = 0; k < HF; ++k) a += sp[k] * Wf1[k * 32 + t];
        sh[t] = fmaxf(a, 0.f);
    }
    __syncthreads();
    if (t < 2) {
        float a = bf2[t];
#pragma unroll
        for (int k = 0; k < 32; ++k) a += sh[k] * Wf2[k * 2 + t];
        out[g * 2 + t] = 1.f / (1.f + expf(-a));
    }
}

extern "C" void kernel_launch(void* const* d_in, const int* in_sizes, int n_in,
                              void* d_out, int out_size, void* d_ws, size_t ws_size,
                              hipStream_t stream) {
    const float* x     = (const float*)d_in[0];
    const int*   ei    = (const int*)d_in[1];
    const int*   batch = (const int*)d_in[2];
    const float* W1 = (const float*)d_in[3];
    const float* b1 = (const float*)d_in[4];
    const float* g1 = (const float*)d_in[5];
    const float* be1 = (const float*)d_in[6];
    const float* rm1 = (const float*)d_in[7];
    const float* rv1 = (const float*)d_in[8];
    const float* W2 = (const float*)d_in[9];
    const float* b2 = (const float*)d_in[10];
    const float* g2 = (const float*)d_in[11];
    const float* be2 = (const float*)d_in[12];
    const float* rm2 = (const float*)d_in[13];
    const float* rv2 = (const float*)d_in[14];
    const float* W3 = (const float*)d_in[15];
    const float* b3 = (const float*)d_in[16];
    const float* g3 = (const float*)d_in[17];
    const float* be3 = (const float*)d_in[18];
    const float* rm3 = (const float*)d_in[19];
    const float* rv3 = (const float*)d_in[20];
    const float* Wf1 = (const float*)d_in[21];
    const float* bf1 = (const float*)d_in[22];
    const float* Wf2 = (const float*)d_in[23];
    const float* bf2 = (const float*)d_in[24];
    float* out = (float*)d_out;

    const int N = in_sizes[2];          // 100000
    const int E = in_sizes[1] / 2;      // 3200000
    const int G = out_size / 2;         // 256

    char* ws = (char*)d_ws;
    size_t off = 0;
    auto alloc = [&](size_t bytes) {
        char* p = ws + off;
        off += (bytes + 255) & ~(size_t)255;
        return p;
    };
    float* A        = (float*)alloc((size_t)N * HF * sizeof(float));  // hw (post-matmul)
    float* B        = (float*)alloc((size_t)N * HF * sizeof(float));  // h (post-layer)
    float* dinv     = (float*)alloc((size_t)N * sizeof(float));
    int*   cnt      = (int*)  alloc((size_t)N * sizeof(int));
    int*   chunk_sc = (int*)  alloc((size_t)N * sizeof(int));
    int*   base     = (int*)  alloc((size_t)N * sizeof(int));
    int*   cursor   = (int*)  alloc((size_t)N * sizeof(int));         // becomes rowend
    int*   bsum     = (int*)  alloc(256 * sizeof(int));
    int*   bbase    = (int*)  alloc(256 * sizeof(int));
    int*   csr_src  = (int*)  alloc((size_t)E * sizeof(int));
    float* csr_w    = (float*)alloc((size_t)E * sizeof(float));

    const int* src = ei;
    const int* dst = ei + E;

    const int BT = 256;
    int gN  = (N + BT - 1) / BT;
    int gE  = (E + BT - 1) / BT;
    int gNF = (N * HF + BT - 1) / BT;
    int NB  = (N + SCAN_B - 1) / SCAN_B;
    int gW  = (N + 3) / 4;   // agg: 4 nodes per 256-thread block

    // ---- CSR build (once per call) ----
    hipMemsetAsync(cnt, 0, (size_t)N * sizeof(int), stream);
    k_hist<<<gE, BT, 0, stream>>>(cnt, dst, E);
    k_dinv<<<gN, BT, 0, stream>>>(dinv, cnt, N);
    k_scan1<<<NB, SCAN_B, 0, stream>>>(cnt, chunk_sc, bsum, N);
    k_scan2<<<1, 64, 0, stream>>>(bsum, bbase, NB);
    k_scan3<<<NB, SCAN_B, 0, stream>>>(chunk_sc, bbase, base, cursor, N);
    k_scatter<<<gE, BT, 0, stream>>>(src, dst, dinv, cursor, csr_src, csr_w, E);
    // after scatter, cursor[n] == base[n] + cnt[n] == row end

    // ---- layer 1 ----
    k_matmul<5><<<gNF, BT, 0, stream>>>(x, W1, A, N);
    k_agg<<<gW, BT, 0, stream>>>(A, B, csr_src, csr_w, base, cursor, dinv,
                                 b1, g1, be1, rm1, rv1, N);
    // ---- layer 2 ----
    k_matmul<64><<<gNF, BT, 0, stream>>>(B, W2, A, N);
    k_agg<<<gW, BT, 0, stream>>>(A, B, csr_src, csr_w, base, cursor, dinv,
                                 b2, g2, be2, rm2, rv2, N);
    // ---- layer 3 ----
    k_matmul<64><<<gNF, BT, 0, stream>>>(B, W3, A, N);
    k_agg<<<gW, BT, 0, stream>>>(A, B, csr_src, csr_w, base, cursor, dinv,
                                 b3, g3, be3, rm3, rv3, N);

    // ---- pool + MLP head ----
    k_pool_fc<<<G, BT, 0, stream>>>(B, batch, Wf1, bf1, Wf2, bf2, out, N);
}

// Round 3
// 1068.757 us; speedup vs baseline: 2.5532x; 1.1451x over previous
//
#include <hip/hip_runtime.h>
#include <hip/hip_bf16.h>

#define HF 64
#define EPS 1e-5f
#define SCAN_B 1024

// ---- histogram of dst (in-degree, excluding self loop) ----
__global__ void k_hist(int* __restrict__ cnt, const int* __restrict__ dst, int E) {
    int e = blockIdx.x * blockDim.x + threadIdx.x;
    if (e < E) atomicAdd(&cnt[dst[e]], 1);
}

// ---- scan stage 1: per-1024-chunk exclusive scan + chunk totals; also dinv ----
__global__ void k_scan1(const int* __restrict__ cnt, int* __restrict__ chunk_scan,
                        int* __restrict__ bsum, float* __restrict__ dinv, int N) {
    __shared__ int tmp[2][SCAN_B];
    int t = threadIdx.x;
    int gid = blockIdx.x * SCAN_B + t;
    int v = (gid < N) ? cnt[gid] : 0;
    if (gid < N) dinv[gid] = rsqrtf((float)v + 1.0f);
    int pi = 0;
    tmp[0][t] = v;
    __syncthreads();
    for (int off = 1; off < SCAN_B; off <<= 1) {
        int val = tmp[pi][t];
        if (t >= off) val += tmp[pi][t - off];
        tmp[pi ^ 1][t] = val;
        pi ^= 1;
        __syncthreads();
    }
    int inc = tmp[pi][t];
    if (gid < N) chunk_scan[gid] = inc - v;
    if (t == SCAN_B - 1) bsum[blockIdx.x] = inc;
}

// ---- scan stage 2: exclusive scan of chunk totals ----
__global__ void k_scan2(const int* __restrict__ bsum, int* __restrict__ bbase, int NB) {
    if (threadIdx.x == 0 && blockIdx.x == 0) {
        int acc = 0;
        for (int i = 0; i < NB; ++i) { bbase[i] = acc; acc += bsum[i]; }
    }
}

// ---- scan stage 3: base = chunk_scan + bbase; cursor = base ----
__global__ void k_scan3(const int* __restrict__ chunk_scan, const int* __restrict__ bbase,
                        int* __restrict__ base, int* __restrict__ cursor, int N) {
    int gid = blockIdx.x * SCAN_B + threadIdx.x;
    if (gid < N) {
        int b = chunk_scan[gid] + bbase[blockIdx.x];
        base[gid] = b;
        cursor[gid] = b;
    }
}

// ---- scatter edges: ONE packed 8B record (src, w) per edge ----
__global__ void k_scatter(const int* __restrict__ src, const int* __restrict__ dst,
                          const float* __restrict__ dinv, int* __restrict__ cursor,
                          long long* __restrict__ csr, int E) {
    int e = blockIdx.x * blockDim.x + threadIdx.x;
    if (e >= E) return;
    int s = src[e], d = dst[e];
    float w = dinv[s] * dinv[d];
    int pos = atomicAdd(&cursor[d], 1);
    long long rec = (long long)(unsigned)s | ((long long)(unsigned)__float_as_uint(w) << 32);
    csr[pos] = rec;
}

// ---- layer 1 fused: agg(x)[N,5] -> @W1 -> +b,BN,ReLU -> hout[N,64] ----
// one wave per node; lanes 0..4 accumulate features during gather; all 64 in matmul.
__global__ __launch_bounds__(256) void k_layer1(
    const float* __restrict__ x, float* __restrict__ hout,
    const long long* __restrict__ csr, const int* __restrict__ base,
    const int* __restrict__ rowend, const float* __restrict__ dinv,
    const float* __restrict__ W1, const float* __restrict__ b,
    const float* __restrict__ g, const float* __restrict__ be,
    const float* __restrict__ rm, const float* __restrict__ rv, int N) {
    __shared__ float sW[5 * HF];
    for (int i = threadIdx.x; i < 5 * HF; i += blockDim.x) sW[i] = W1[i];
    __syncthreads();

    int node = blockIdx.x * (blockDim.x >> 6) + (threadIdx.x >> 6);
    int lane = threadIdx.x & 63;
    if (node >= N) return;

    int j = base[node], end = rowend[node];
    float acc = 0.f;
    while (j < end) {
        int chunk = end - j; if (chunk > 64) chunk = 64;
        int s = 0; float w = 0.f;
        if (lane < chunk) {
            long long rec = csr[j + lane];
            s = (int)(rec & 0xffffffffLL);
            w = __uint_as_float((unsigned)(unsigned long long)(rec >> 32));
        }
#pragma unroll 8
        for (int k = 0; k < chunk; ++k) {
            int ss = __shfl(s, k, 64);
            float ww = __shfl(w, k, 64);
            if (lane < 5) acc += x[ss * 5 + lane] * ww;
        }
        j += chunk;
    }
    float di = dinv[node];
    if (lane < 5) acc += x[node * 5 + lane] * di * di;

    float out = b[lane];
#pragma unroll
    for (int k = 0; k < 5; ++k) {
        float hk = __shfl(acc, k, 64);
        out += hk * sW[k * HF + lane];
    }
    float scale = g[lane] * rsqrtf(rv[lane] + EPS);
    out = (out - rm[lane]) * scale + be[lane];
    hout[node * HF + lane] = fmaxf(out, 0.f);
}

// ---- layers 2/3 fused: agg(h)[N,64] -> @W(64x64) -> +b,BN,ReLU -> hout ----
__global__ __launch_bounds__(256) void k_layer(
    const float* __restrict__ h, float* __restrict__ hout,
    const long long* __restrict__ csr, const int* __restrict__ base,
    const int* __restrict__ rowend, const float* __restrict__ dinv,
    const float* __restrict__ W, const float* __restrict__ b,
    const float* __restrict__ g, const float* __restrict__ be,
    const float* __restrict__ rm, const float* __restrict__ rv, int N) {
    __shared__ float sW[HF * HF];
    for (int i = threadIdx.x; i < HF * HF; i += blockDim.x) sW[i] = W[i];
    __syncthreads();

    int node = blockIdx.x * (blockDim.x >> 6) + (threadIdx.x >> 6);
    int lane = threadIdx.x & 63;
    if (node >= N) return;

    int j = base[node], end = rowend[node];
    float acc = 0.f;
    while (j < end) {
        int chunk = end - j; if (chunk > 64) chunk = 64;
        int s = 0; float w = 0.f;
        if (lane < chunk) {
            long long rec = csr[j + lane];
            s = (int)(rec & 0xffffffffLL);
            w = __uint_as_float((unsigned)(unsigned long long)(rec >> 32));
        }
#pragma unroll 8
        for (int k = 0; k < chunk; ++k) {
            int ss = __shfl(s, k, 64);
            float ww = __shfl(w, k, 64);
            acc += h[ss * HF + lane] * ww;
        }
        j += chunk;
    }
    float di = dinv[node];
    acc += h[node * HF + lane] * di * di;

    // out_f = b[f] + sum_k acc_k * W[k][f]
    float out = b[lane];
#pragma unroll 8
    for (int k = 0; k < HF; ++k) {
        float hk = __shfl(acc, k, 64);
        out += hk * sW[k * HF + lane];
    }
    float scale = g[lane] * rsqrtf(rv[lane] + EPS);
    out = (out - rm[lane]) * scale + be[lane];
    hout[node * HF + lane] = fmaxf(out, 0.f);
}

// ---- per-graph mean-pool + FC(64->32) relu + FC(32->2) sigmoid ----
__global__ void k_pool_fc(const float* __restrict__ h, const int* __restrict__ batch,
                          const float* __restrict__ Wf1, const float* __restrict__ bf1,
                          const float* __restrict__ Wf2, const float* __restrict__ bf2,
                          float* __restrict__ out, int N) {
    int g = blockIdx.x;
    int t = threadIdx.x;
    int f = t & 63, q = t >> 6;

    int lo = 0, hi = N;
    while (lo < hi) { int mid = (lo + hi) >> 1; if (batch[mid] < g) lo = mid + 1; else hi = mid; }
    int start = lo;
    hi = N;
    while (lo < hi) { int mid = (lo + hi) >> 1; if (batch[mid] < g + 1) lo = mid + 1; else hi = mid; }
    int end = lo;

    float sum = 0.f;
    for (int n = start + q; n < end; n += 4) sum += h[n * HF + f];

    __shared__ float red[4][HF];
    __shared__ float sp[HF];
    __shared__ float sh[32];
    red[q][f] = sum;
    __syncthreads();
    if (q == 0) {
        float s = red[0][f] + red[1][f] + red[2][f] + red[3][f];
        float cntf = (float)(end - start);
        sp[f] = s / fmaxf(cntf, 1.0f);
    }
    __syncthreads();
    if (t < 32) {
        float a = bf1[t];
#pragma unroll
        for (int k = 0; k < HF; ++k) a += sp[k] * Wf1[k * 32 + t];
        sh[t] = fmaxf(a, 0.f);
    }
    __syncthreads();
    if (t < 2) {
        float a = bf2[t];
#pragma unroll
        for (int k = 0; k < 32; ++k) a += sh[k] * Wf2[k * 2 + t];
        out[g * 2 + t] = 1.f / (1.f + expf(-a));
    }
}

extern "C" void kernel_launch(void* const* d_in, const int* in_sizes, int n_in,
                              void* d_out, int out_size, void* d_ws, size_t ws_size,
                              hipStream_t stream) {
    const float* x     = (const float*)d_in[0];
    const int*   ei    = (const int*)d_in[1];
    const int*   batch = (const int*)d_in[2];
    const float* W1 = (const float*)d_in[3];
    const float* b1 = (const float*)d_in[4];
    const float* g1 = (const float*)d_in[5];
    const float* be1 = (const float*)d_in[6];
    const float* rm1 = (const float*)d_in[7];
    const float* rv1 = (const float*)d_in[8];
    const float* W2 = (const float*)d_in[9];
    const float* b2 = (const float*)d_in[10];
    const float* g2 = (const float*)d_in[11];
    const float* be2 = (const float*)d_in[12];
    const float* rm2 = (const float*)d_in[13];
    const float* rv2 = (const float*)d_in[14];
    const float* W3 = (const float*)d_in[15];
    const float* b3 = (const float*)d_in[16];
    const float* g3 = (const float*)d_in[17];
    const float* be3 = (const float*)d_in[18];
    const float* rm3 = (const float*)d_in[19];
    const float* rv3 = (const float*)d_in[20];
    const float* Wf1 = (const float*)d_in[21];
    const float* bf1 = (const float*)d_in[22];
    const float* Wf2 = (const float*)d_in[23];
    const float* bf2 = (const float*)d_in[24];
    float* out = (float*)d_out;

    const int N = in_sizes[2];          // 100000
    const int E = in_sizes[1] / 2;      // 3200000
    const int G = out_size / 2;         // 256

    char* ws = (char*)d_ws;
    size_t off = 0;
    auto alloc = [&](size_t bytes) {
        char* p = ws + off;
        off += (bytes + 255) & ~(size_t)255;
        return p;
    };
    float*     A        = (float*)alloc((size_t)N * HF * sizeof(float));
    float*     B        = (float*)alloc((size_t)N * HF * sizeof(float));
    float*     dinv     = (float*)alloc((size_t)N * sizeof(float));
    int*       cnt      = (int*)  alloc((size_t)N * sizeof(int));
    int*       chunk_sc = (int*)  alloc((size_t)N * sizeof(int));
    int*       base     = (int*)  alloc((size_t)N * sizeof(int));
    int*       cursor   = (int*)  alloc((size_t)N * sizeof(int));   // becomes rowend
    int*       bsum     = (int*)  alloc(256 * sizeof(int));
    int*       bbase    = (int*)  alloc(256 * sizeof(int));
    long long* csr      = (long long*)alloc((size_t)E * sizeof(long long));

    const int* src = ei;
    const int* dst = ei + E;

    const int BT = 256;
    int gE  = (E + BT - 1) / BT;
    int NB  = (N + SCAN_B - 1) / SCAN_B;
    int gW  = (N + 3) / 4;   // 4 nodes (waves) per 256-thread block

    // ---- CSR build ----
    hipMemsetAsync(cnt, 0, (size_t)N * sizeof(int), stream);
    k_hist<<<gE, BT, 0, stream>>>(cnt, dst, E);
    k_scan1<<<NB, SCAN_B, 0, stream>>>(cnt, chunk_sc, bsum, dinv, N);
    k_scan2<<<1, 64, 0, stream>>>(bsum, bbase, NB);
    k_scan3<<<NB, SCAN_B, 0, stream>>>(chunk_sc, bbase, base, cursor, N);
    k_scatter<<<gE, BT, 0, stream>>>(src, dst, dinv, cursor, csr, E);
    // cursor[n] now == row end

    // ---- layers (agg-first; agg(h)@W == agg(h@W) by linearity) ----
    k_layer1<<<gW, BT, 0, stream>>>(x, B, csr, base, cursor, dinv,
                                    W1, b1, g1, be1, rm1, rv1, N);
    k_layer<<<gW, BT, 0, stream>>>(B, A, csr, base, cursor, dinv,
                                   W2, b2, g2, be2, rm2, rv2, N);
    k_layer<<<gW, BT, 0, stream>>>(A, B, csr, base, cursor, dinv,
                                   W3, b3, g3, be3, rm3, rv3, N);

    // ---- pool + MLP head ----
    k_pool_fc<<<G, BT, 0, stream>>>(B, batch, Wf1, bf1, Wf2, bf2, out, N);
}

// Round 4
// 970.203 us; speedup vs baseline: 2.8125x; 1.1016x over previous
//
#include <hip/hip_runtime.h>
#include <hip/hip_bf16.h>

#define HF 64
#define EPS 1e-5f
#define SCAN_B 1024

typedef __hip_bfloat16 bf16;

// ---- histogram of dst (in-degree, excluding self loop) ----
__global__ void k_hist(int* __restrict__ cnt, const int* __restrict__ dst, int E) {
    int e = blockIdx.x * blockDim.x + threadIdx.x;
    if (e < E) atomicAdd(&cnt[dst[e]], 1);
}

// ---- scan stage 1: per-1024-chunk exclusive scan + chunk totals; also dinv ----
__global__ void k_scan1(const int* __restrict__ cnt, int* __restrict__ chunk_scan,
                        int* __restrict__ bsum, float* __restrict__ dinv, int N) {
    __shared__ int tmp[2][SCAN_B];
    int t = threadIdx.x;
    int gid = blockIdx.x * SCAN_B + t;
    int v = (gid < N) ? cnt[gid] : 0;
    if (gid < N) dinv[gid] = rsqrtf((float)v + 1.0f);
    int pi = 0;
    tmp[0][t] = v;
    __syncthreads();
    for (int off = 1; off < SCAN_B; off <<= 1) {
        int val = tmp[pi][t];
        if (t >= off) val += tmp[pi][t - off];
        tmp[pi ^ 1][t] = val;
        pi ^= 1;
        __syncthreads();
    }
    int inc = tmp[pi][t];
    if (gid < N) chunk_scan[gid] = inc - v;
    if (t == SCAN_B - 1) bsum[blockIdx.x] = inc;
}

// ---- scan stage 2: exclusive scan of chunk totals ----
__global__ void k_scan2(const int* __restrict__ bsum, int* __restrict__ bbase, int NB) {
    if (threadIdx.x == 0 && blockIdx.x == 0) {
        int acc = 0;
        for (int i = 0; i < NB; ++i) { bbase[i] = acc; acc += bsum[i]; }
    }
}

// ---- scan stage 3: base = chunk_scan + bbase; cursor = base ----
__global__ void k_scan3(const int* __restrict__ chunk_scan, const int* __restrict__ bbase,
                        int* __restrict__ base, int* __restrict__ cursor, int N) {
    int gid = blockIdx.x * SCAN_B + threadIdx.x;
    if (gid < N) {
        int b = chunk_scan[gid] + bbase[blockIdx.x];
        base[gid] = b;
        cursor[gid] = b;
    }
}

// ---- scatter edges: ONE 4B record (src only) per edge ----
__global__ void k_scatter(const int* __restrict__ src, const int* __restrict__ dst,
                          int* __restrict__ cursor, int* __restrict__ csr_src, int E) {
    int e = blockIdx.x * blockDim.x + threadIdx.x;
    if (e >= E) return;
    int d = dst[e];
    int pos = atomicAdd(&cursor[d], 1);
    csr_src[pos] = src[e];
}

// ---- prescale: xs[n,c] = x[n,c] * dinv[n] ----
__global__ void k_prescale(const float* __restrict__ x, const float* __restrict__ dinv,
                           float* __restrict__ xs, int N5) {
    int i = blockIdx.x * blockDim.x + threadIdx.x;
    if (i < N5) xs[i] = x[i] * dinv[i / 5];
}

// ---- layer 1 fused: dinv[d]*(sum xs[s] + xs[d]) -> @W1 -> BN,ReLU -> hs1 (bf16, pre-scaled) ----
__global__ __launch_bounds__(256) void k_layer1(
    const float* __restrict__ xs, bf16* __restrict__ hout,
    const int* __restrict__ csr, const int* __restrict__ basep,
    const int* __restrict__ rowend, const float* __restrict__ dinv,
    const float* __restrict__ W1, const float* __restrict__ b,
    const float* __restrict__ g, const float* __restrict__ be,
    const float* __restrict__ rm, const float* __restrict__ rv, int N) {
    __shared__ float sW[5 * HF];
    for (int i = threadIdx.x; i < 5 * HF; i += blockDim.x) sW[i] = W1[i];
    __syncthreads();

    int node = blockIdx.x * (blockDim.x >> 6) + (threadIdx.x >> 6);
    int lane = threadIdx.x & 63;
    if (node >= N) return;

    int j   = __builtin_amdgcn_readfirstlane(basep[node]);
    int end = __builtin_amdgcn_readfirstlane(rowend[node]);

    float acc = 0.f;
    if (lane < 5) acc = xs[node * 5 + lane];   // self term
#pragma unroll 4
    for (; j < end; ++j) {
        int s = csr[j];                        // wave-uniform -> scalar load
        if (lane < 5) acc += xs[s * 5 + lane];
    }
    float di = dinv[node];
    acc *= di;

    float out = b[lane];
#pragma unroll
    for (int k = 0; k < 5; ++k) out += __shfl(acc, k, 64) * sW[k * HF + lane];
    out = (out - rm[lane]) * (g[lane] * rsqrtf(rv[lane] + EPS)) + be[lane];
    out = fmaxf(out, 0.f);
    hout[node * HF + lane] = __float2bfloat16(out * di);   // pre-scale for next layer
}

// ---- layers 2/3 fused: dinv[d]*(sum hs[s] + hs[d]) -> @W -> BN,ReLU ----
// SCALE_OUT=1: write bf16 hs = h*dinv (feeds next layer). SCALE_OUT=0: write fp32 h (feeds pool).
template <int SCALE_OUT>
__global__ __launch_bounds__(256) void k_layer(
    const bf16* __restrict__ hs, void* __restrict__ hout_v,
    const int* __restrict__ csr, const int* __restrict__ basep,
    const int* __restrict__ rowend, const float* __restrict__ dinv,
    const float* __restrict__ W, const float* __restrict__ b,
    const float* __restrict__ g, const float* __restrict__ be,
    const float* __restrict__ rm, const float* __restrict__ rv, int N) {
    __shared__ float sW[HF * HF];
    for (int i = threadIdx.x; i < HF * HF; i += blockDim.x) sW[i] = W[i];
    __syncthreads();

    int node = blockIdx.x * (blockDim.x >> 6) + (threadIdx.x >> 6);
    int lane = threadIdx.x & 63;
    if (node >= N) return;

    int j   = __builtin_amdgcn_readfirstlane(basep[node]);
    int end = __builtin_amdgcn_readfirstlane(rowend[node]);

    float acc = __bfloat162float(hs[node * HF + lane]);    // self term (already *dinv)
#pragma unroll 4
    for (; j < end; ++j) {
        int s = csr[j];                                    // wave-uniform -> scalar load
        acc += __bfloat162float(hs[s * HF + lane]);
    }
    float di = dinv[node];
    acc *= di;

    float out = b[lane];
#pragma unroll
    for (int k = 0; k < HF; ++k) out += __shfl(acc, k, 64) * sW[k * HF + lane];
    out = (out - rm[lane]) * (g[lane] * rsqrtf(rv[lane] + EPS)) + be[lane];
    out = fmaxf(out, 0.f);
    if (SCALE_OUT) {
        ((bf16*)hout_v)[node * HF + lane] = __float2bfloat16(out * di);
    } else {
        ((float*)hout_v)[node * HF + lane] = out;
    }
}

// ---- per-graph mean-pool + FC(64->32) relu + FC(32->2) sigmoid ----
__global__ void k_pool_fc(const float* __restrict__ h, const int* __restrict__ batch,
                          const float* __restrict__ Wf1, const float* __restrict__ bf1,
                          const float* __restrict__ Wf2, const float* __restrict__ bf2,
                          float* __restrict__ out, int N) {
    int g = blockIdx.x;
    int t = threadIdx.x;
    int f = t & 63, q = t >> 6;

    int lo = 0, hi = N;
    while (lo < hi) { int mid = (lo + hi) >> 1; if (batch[mid] < g) lo = mid + 1; else hi = mid; }
    int start = lo;
    hi = N;
    while (lo < hi) { int mid = (lo + hi) >> 1; if (batch[mid] < g + 1) lo = mid + 1; else hi = mid; }
    int end = lo;

    float sum = 0.f;
    for (int n = start + q; n < end; n += 4) sum += h[n * HF + f];

    __shared__ float red[4][HF];
    __shared__ float sp[HF];
    __shared__ float sh[32];
    red[q][f] = sum;
    __syncthreads();
    if (q == 0) {
        float s = red[0][f] + red[1][f] + red[2][f] + red[3][f];
        float cntf = (float)(end - start);
        sp[f] = s / fmaxf(cntf, 1.0f);
    }
    __syncthreads();
    if (t < 32) {
        float a = bf1[t];
#pragma unroll
        for (int k = 0; k < HF; ++k) a += sp[k] * Wf1[k * 32 + t];
        sh[t] = fmaxf(a, 0.f);
    }
    __syncthreads();
    if (t < 2) {
        float a = bf2[t];
#pragma unroll
        for (int k = 0; k < 32; ++k) a += sh[k] * Wf2[k * 2 + t];
        out[g * 2 + t] = 1.f / (1.f + expf(-a));
    }
}

extern "C" void kernel_launch(void* const* d_in, const int* in_sizes, int n_in,
                              void* d_out, int out_size, void* d_ws, size_t ws_size,
                              hipStream_t stream) {
    const float* x     = (const float*)d_in[0];
    const int*   ei    = (const int*)d_in[1];
    const int*   batch = (const int*)d_in[2];
    const float* W1 = (const float*)d_in[3];
    const float* b1 = (const float*)d_in[4];
    const float* g1 = (const float*)d_in[5];
    const float* be1 = (const float*)d_in[6];
    const float* rm1 = (const float*)d_in[7];
    const float* rv1 = (const float*)d_in[8];
    const float* W2 = (const float*)d_in[9];
    const float* b2 = (const float*)d_in[10];
    const float* g2 = (const float*)d_in[11];
    const float* be2 = (const float*)d_in[12];
    const float* rm2 = (const float*)d_in[13];
    const float* rv2 = (const float*)d_in[14];
    const float* W3 = (const float*)d_in[15];
    const float* b3 = (const float*)d_in[16];
    const float* g3 = (const float*)d_in[17];
    const float* be3 = (const float*)d_in[18];
    const float* rm3 = (const float*)d_in[19];
    const float* rv3 = (const float*)d_in[20];
    const float* Wf1 = (const float*)d_in[21];
    const float* bf1 = (const float*)d_in[22];
    const float* Wf2 = (const float*)d_in[23];
    const float* bf2 = (const float*)d_in[24];
    float* out = (float*)d_out;

    const int N = in_sizes[2];          // 100000
    const int E = in_sizes[1] / 2;      // 3200000
    const int G = out_size / 2;         // 256

    char* ws = (char*)d_ws;
    size_t off = 0;
    auto alloc = [&](size_t bytes) {
        char* p = ws + off;
        off += (bytes + 255) & ~(size_t)255;
        return p;
    };
    float* H3       = (float*)alloc((size_t)N * HF * sizeof(float));   // fp32 layer-3 out
    bf16*  HS1      = (bf16*) alloc((size_t)N * HF * sizeof(bf16));
    bf16*  HS2      = (bf16*) alloc((size_t)N * HF * sizeof(bf16));
    float* xs       = (float*)alloc((size_t)N * 5 * sizeof(float));
    float* dinv     = (float*)alloc((size_t)N * sizeof(float));
    int*   cnt      = (int*)  alloc((size_t)N * sizeof(int));
    int*   chunk_sc = (int*)  alloc((size_t)N * sizeof(int));
    int*   base     = (int*)  alloc((size_t)N * sizeof(int));
    int*   cursor   = (int*)  alloc((size_t)N * sizeof(int));   // becomes rowend
    int*   bsum     = (int*)  alloc(256 * sizeof(int));
    int*   bbase    = (int*)  alloc(256 * sizeof(int));
    int*   csr      = (int*)  alloc((size_t)E * sizeof(int));

    const int* src = ei;
    const int* dst = ei + E;

    const int BT = 256;
    int gE  = (E + BT - 1) / BT;
    int NB  = (N + SCAN_B - 1) / SCAN_B;
    int gW  = (N + 3) / 4;
    int gP  = (N * 5 + BT - 1) / BT;

    // ---- CSR build ----
    hipMemsetAsync(cnt, 0, (size_t)N * sizeof(int), stream);
    k_hist<<<gE, BT, 0, stream>>>(cnt, dst, E);
    k_scan1<<<NB, SCAN_B, 0, stream>>>(cnt, chunk_sc, bsum, dinv, N);
    k_scan2<<<1, 64, 0, stream>>>(bsum, bbase, NB);
    k_scan3<<<NB, SCAN_B, 0, stream>>>(chunk_sc, bbase, base, cursor, N);
    k_scatter<<<gE, BT, 0, stream>>>(src, dst, cursor, csr, E);
    k_prescale<<<gP, BT, 0, stream>>>(x, dinv, xs, N * 5);
    // cursor[n] now == row end

    // ---- fused layers ----
    k_layer1<<<gW, BT, 0, stream>>>(xs, HS1, csr, base, cursor, dinv,
                                    W1, b1, g1, be1, rm1, rv1, N);
    k_layer<1><<<gW, BT, 0, stream>>>(HS1, HS2, csr, base, cursor, dinv,
                                      W2, b2, g2, be2, rm2, rv2, N);
    k_layer<0><<<gW, BT, 0, stream>>>(HS2, H3, csr, base, cursor, dinv,
                                      W3, b3, g3, be3, rm3, rv3, N);

    // ---- pool + MLP head ----
    k_pool_fc<<<G, BT, 0, stream>>>(H3, batch, Wf1, bf1, Wf2, bf2, out, N);
}